// Round 1
// baseline (62.914 us; speedup 1.0000x reference)
//
#include <hip/hip_runtime.h>

typedef __attribute__((ext_vector_type(8)))  short   short8;
typedef __attribute__((ext_vector_type(4)))  unsigned uint4v;
typedef __attribute__((ext_vector_type(16))) float   f32x16;

typedef const __attribute__((address_space(1))) unsigned cglb_u32;
typedef __attribute__((address_space(3))) unsigned lds_u32;

constexpr int GRAM_BLOCKS = 256;
constexpr int MSE_BLOCKS  = 256;
constexpr int BLOCK       = 128;          // 2 waves
constexpr int SLAB_F      = 192;          // floats per (o,c) slab: 64 rows x 3
constexpr int CHUNK_SLABS = 16;
constexpr int CHUNK_F     = CHUNK_SLABS * SLAB_F;      // 3072 floats = 12 KiB
constexpr int NSLAB       = 512 * 512;                 // 262144
constexpr int NCHUNK      = NSLAB / CHUNK_SLABS;       // 16384
constexpr int GRAM_WAVES  = GRAM_BLOCKS * (BLOCK / 64); // 512
constexpr int CHUNKS_PER_WAVE = NCHUNK / GRAM_WAVES;   // 32
constexpr unsigned MSE_N4 = 2097152u;                  // 8388608 floats / 4
constexpr int MSE_THREADS = MSE_BLOCKS * BLOCK;        // 32768

// ws layout (floats): [0] mse_sum ; [64 .. 64+3072) tile-encoded gram partial sums
// tile-encode: e = tile*1024 + reg*64 + lane ; tile 0 = G[0:32][0:32],
// 1 = G[0:32][32:64] (counted twice in finalize), 2 = G[32:64][32:64]

__device__ __forceinline__ unsigned pk_bf16(float a, float b) {
  unsigned ua = (__builtin_bit_cast(unsigned, a) + 0x8000u) >> 16;
  unsigned ub = (__builtin_bit_cast(unsigned, b) + 0x8000u) & 0xFFFF0000u;
  return ua | ub;
}

__device__ __forceinline__ void stage_chunk(const float* g, float* buf, int lane) {
#pragma unroll
  for (int i = 0; i < 12; ++i) {
    __builtin_amdgcn_global_load_lds(
        (cglb_u32*)(const unsigned*)(g + i * 256 + lane * 4),
        (lds_u32*)(unsigned*)(buf + i * 256),
        16, 0, 0);
  }
}

__global__ __launch_bounds__(BLOCK) void k_main(
    const float* __restrict__ X, const float* __restrict__ Y,
    const float* __restrict__ W, float* __restrict__ ws) {
  __shared__ float lds[2][2][CHUNK_F];   // [wave][buf][chunk floats] = 48 KiB
  const int bid = blockIdx.x;
  const int tid = threadIdx.x;

  if (bid >= GRAM_BLOCKS) {
    // ---------------- MSE partial ----------------
    const int t0 = (bid - GRAM_BLOCKS) * BLOCK + tid;
    const float4* x4 = (const float4*)X;
    const float4* y4 = (const float4*)Y;
    float acc = 0.f;
    for (unsigned i = (unsigned)t0; i < MSE_N4; i += (unsigned)MSE_THREADS) {
      float4 a = x4[i], b = y4[i];
      float d0 = a.x - b.x, d1 = a.y - b.y, d2 = a.z - b.z, d3 = a.w - b.w;
      acc += d0 * d0 + d1 * d1 + d2 * d2 + d3 * d3;
    }
#pragma unroll
    for (int o = 32; o; o >>= 1) acc += __shfl_xor(acc, o, 64);
    if ((tid & 63) == 0) atomicAdd(&ws[0], acc);
    return;
  }

  // ---------------- Gram partial (per-wave independent stream) ----------------
  const int wave = tid >> 6;
  const int lane = tid & 63;
  const int r    = lane & 31;
  const int hi   = lane >> 5;
  const int wg   = bid * 2 + wave;
  const int c0   = wg * CHUNKS_PER_WAVE;

  float* b0 = &lds[wave][0][0];
  float* b1 = &lds[wave][1][0];

  stage_chunk(W + (size_t)c0 * CHUNK_F, b0, lane);

  f32x16 a00{}, a01{}, a11{};

  for (int t = 0; t < CHUNKS_PER_WAVE; ++t) {
    float* cur = (t & 1) ? b1 : b0;
    if (t + 1 < CHUNKS_PER_WAVE) {
      stage_chunk(W + (size_t)(c0 + t + 1) * CHUNK_F, (t & 1) ? b0 : b1, lane);
      asm volatile("s_waitcnt vmcnt(12)" ::: "memory");
    } else {
      asm volatile("s_waitcnt vmcnt(0)" ::: "memory");
    }
    __builtin_amdgcn_sched_barrier(0);

    // Build bf16 fragments: F_lo rows 0..31 (this lane: row r), F_hi rows 32..63.
    // Lane-half hi owns slabs hi*8 .. hi*8+7 of the 16-slab chunk (k-map freedom:
    // any (lane,reg)->u mapping is gram-invariant since A and B share it).
    unsigned fl[3][4], fh[3][4];
#pragma unroll
    for (int bp = 0; bp < 4; ++bp) {
      const float* sA = cur + (hi * 8 + 2 * bp) * SLAB_F + r * 3;
      const float* sB = sA + SLAB_F;
      float a0 = sA[0],  a1 = sA[1],  a2 = sA[2];
      float c0f = sA[96], c1f = sA[97], c2f = sA[98];   // row r+32
      float b0f = sB[0],  b1f = sB[1],  b2f = sB[2];
      float d0f = sB[96], d1f = sB[97], d2f = sB[98];
      fl[0][bp] = pk_bf16(a0, b0f);
      fl[1][bp] = pk_bf16(a1, b1f);
      fl[2][bp] = pk_bf16(a2, b2f);
      fh[0][bp] = pk_bf16(c0f, d0f);
      fh[1][bp] = pk_bf16(c1f, d1f);
      fh[2][bp] = pk_bf16(c2f, d2f);
    }
#pragma unroll
    for (int k = 0; k < 3; ++k) {
      uint4v vl = {fl[k][0], fl[k][1], fl[k][2], fl[k][3]};
      uint4v vh = {fh[k][0], fh[k][1], fh[k][2], fh[k][3]};
      short8 lo = __builtin_bit_cast(short8, vl);
      short8 hv = __builtin_bit_cast(short8, vh);
      a00 = __builtin_amdgcn_mfma_f32_32x32x16_bf16(lo, lo, a00, 0, 0, 0);
      a01 = __builtin_amdgcn_mfma_f32_32x32x16_bf16(lo, hv, a01, 0, 0, 0);
      a11 = __builtin_amdgcn_mfma_f32_32x32x16_bf16(hv, hv, a11, 0, 0, 0);
    }
  }

  // ---------------- block reduce (2 waves) + atomic to global ----------------
  __syncthreads();                 // both waves done with their LDS buffers
  float* red = &lds[0][0][0];
  const int base = wave * 3072;
#pragma unroll
  for (int rg = 0; rg < 16; ++rg) {
    red[base +        rg * 64 + lane] = a00[rg];
    red[base + 1024 + rg * 64 + lane] = a01[rg];
    red[base + 2048 + rg * 64 + lane] = a11[rg];
  }
  __syncthreads();
  float* gram = ws + 64;
  for (int e = tid; e < 3072; e += BLOCK)
    atomicAdd(&gram[e], red[e] + red[3072 + e]);
}

__global__ __launch_bounds__(256) void k_fin(const float* __restrict__ ws,
                                             float* __restrict__ out) {
  __shared__ float g[3072];
  __shared__ float n2[64];
  __shared__ float wsum[4];
  const int tid = threadIdx.x;

  for (int e = tid; e < 3072; e += 256) g[e] = ws[64 + e];
  __syncthreads();

  // diag extraction: C/D layout of 32x32 mfma: col = lane&31,
  // row = (reg&3) + 8*(reg>>2) + 4*(lane>>5)
  for (int e = tid; e < 3072; e += 256) {
    int tl = e >> 10, rg = (e >> 6) & 15, l = e & 63;
    int il = (rg & 3) + 8 * (rg >> 2) + 4 * (l >> 5);
    int jl = l & 31;
    if (tl != 1 && il == jl) n2[il + (tl == 2 ? 32 : 0)] = g[e];
  }
  __syncthreads();

  float local = 0.f;
  for (int e = tid; e < 3072; e += 256) {
    int tl = e >> 10, rg = (e >> 6) & 15, l = e & 63;
    int il = (rg & 3) + 8 * (rg >> 2) + 4 * (l >> 5);
    int jl = l & 31;
    int i, j; float wgt;
    if (tl == 0)      { i = il;      j = jl;      wgt = 1.f; }
    else if (tl == 1) { i = il;      j = jl + 32; wgt = 2.f; }  // symmetric quadrant
    else              { i = il + 32; j = jl + 32; wgt = 1.f; }
    if (i != j) {
      float sim = g[e] / sqrtf(n2[i] * n2[j]);
      if (sim > 0.2f && sim <= 1.0f) local += wgt * sim;
    }
  }
#pragma unroll
  for (int o = 32; o; o >>= 1) local += __shfl_xor(local, o, 64);
  if ((tid & 63) == 0) wsum[tid >> 6] = local;
  __syncthreads();
  if (tid == 0) {
    float reg_sum = wsum[0] + wsum[1] + wsum[2] + wsum[3];
    out[0] = ws[0] * (1.0f / 8388608.0f) + 0.0005f * reg_sum;
  }
}

extern "C" void kernel_launch(void* const* d_in, const int* in_sizes, int n_in,
                              void* d_out, int out_size, void* d_ws, size_t ws_size,
                              hipStream_t stream) {
  const float* X = (const float*)d_in[0];
  const float* Y = (const float*)d_in[1];
  const float* W = (const float*)d_in[2];
  float* ws = (float*)d_ws;

  hipMemsetAsync(d_ws, 0, (64 + 3072) * sizeof(float), stream);
  k_main<<<GRAM_BLOCKS + MSE_BLOCKS, BLOCK, 0, stream>>>(X, Y, W, ws);
  k_fin<<<1, 256, 0, stream>>>(ws, (float*)d_out);
}